// Round 4
// baseline (66052.563 us; speedup 1.0000x reference)
//
#include <hip/hip_runtime.h>
#include <cstdint>
#include <cstddef>

// FBRNN: T=16384, F=2048, H=16, A=64, L=6, G=3H=48.
// R12: single-round-trip stamped handoffs + deadline-aware block assignment.
//  - nsS rows stamped (stamp word at slot 16, row stride 20): consumer issues
//    stamp-read FIRST then data reads in one batch; per-wave in-order DS
//    execution => stamp fresh implies data fresh. flagNs deleted.
//  - partS/recS carry their stamp inside the same 16B record (single b128).
//  - recs carry h-1 (chain folds ns = fma(-2(1-z), R, 1+z*(h-1))).
//  - fc + streamer merged on w4 (chunk data register-prefetched a chunk early).
// Role map:
//   w0 = chain (layers 0-5 + row0/row1 j5 tails + finalize)
//   w4 = streamer (reg-prefetch) + fc head
//   w1 = r0{j0,j3}->P0A(s0), r2{j4}->P2C(s8)
//   w2 = r0{j1,j4}->P0B(s1), tail r3: j5 + merge{s9,s10} -> rec3
//   w3 = r1{j1,j4}->P1A(s3), tail r4: j5 + merge{s11}    -> rec4
//   w5 = r0{j2}->P0C(s2), r1{j3}->P1C(s5), tail r2: j5 + merge{s6,s7,s8} -> rec2
//   w6 = r1{j2}->P1B(s4), r2{j3}->P2B(s7), r3{j4}->P3B(s10)
//   w7 = r2{j2}->P2A(s6), r3{j3}->P3A(s9), r4{j4}->P4A(s11)
// Chain merges row0 partials {s0,s1,s2}+own j5, row1 {s3,s4,s5}+own j5.

#define TT 16384
#define FF 2048
#define HH 16
#define LL 6
#define GG 48
#define CHUNK 64
#define NSR 20
#define LOG2E 1.44269504088896340736f

__device__ float g_gi0p[(TT + CHUNK) * 64];

__device__ __forceinline__ float exp2_(float x) { return __builtin_amdgcn_exp2f(x); }
__device__ __forceinline__ float rcp_(float x) { return __builtin_amdgcn_rcpf(x); }
__device__ __forceinline__ float sig_n(float s) { return rcp_(1.f + exp2_(s)); }
__device__ __forceinline__ float tanh_p(float s) { return fmaf(-2.f, rcp_(exp2_(s) + 1.f), 1.f); }

#define MEMBAR() __asm__ __volatile__("" ::: "memory")

__device__ __forceinline__ float rdlane(float v, int l) {
  union { float f; int i; } a, b;
  a.f = v; b.i = __builtin_amdgcn_readlane(a.i, l); return b.f;
}
template <int CTRL>
__device__ __forceinline__ float dppf(float v) {
  union { float f; int i; } a, b;
  a.f = v; b.i = __builtin_amdgcn_mov_dpp(a.i, CTRL, 0xF, 0xF, true); return b.f;
}
template <int Q>
__device__ __forceinline__ float qbcast(float v) { return dppf<Q | (Q << 2) | (Q << 4) | (Q << 6)>(v); }

__device__ __forceinline__ float rowsum16(float v) {
  v += dppf<0xB1>(v);
  v += dppf<0x4E>(v);
  v += dppf<0x141>(v);
  v += dppf<0x140>(v);
  return v;
}
__device__ __forceinline__ float dot16r(const float (&w)[16], const float (&h)[16]) {
  float s0 = w[0] * h[0], s1 = w[1] * h[1], s2 = w[2] * h[2], s3 = w[3] * h[3];
#pragma unroll
  for (int k = 4; k < 16; k += 4) {
    s0 = fmaf(w[k], h[k], s0);       s1 = fmaf(w[k + 1], h[k + 1], s1);
    s2 = fmaf(w[k + 2], h[k + 2], s2); s3 = fmaf(w[k + 3], h[k + 3], s3);
  }
  return (s0 + s1) + (s2 + s3);
}
__device__ __forceinline__ float dot16i(const float (&w)[16], const float (&h)[16], float init) {
  float s0 = fmaf(w[0], h[0], init), s1 = w[1] * h[1], s2 = w[2] * h[2], s3 = w[3] * h[3];
#pragma unroll
  for (int k = 4; k < 16; k += 4) {
    s0 = fmaf(w[k], h[k], s0);       s1 = fmaf(w[k + 1], h[k + 1], s1);
    s2 = fmaf(w[k + 2], h[k + 2], s2); s3 = fmaf(w[k + 3], h[k + 3], s3);
  }
  return (s0 + s1) + (s2 + s3);
}

__device__ __forceinline__ int ldAcq(int* f) {
  return __hip_atomic_load(f, __ATOMIC_ACQUIRE, __HIP_MEMORY_SCOPE_WORKGROUP);
}
__device__ __forceinline__ int ldRlx(int* f) {
  return __hip_atomic_load(f, __ATOMIC_RELAXED, __HIP_MEMORY_SCOPE_WORKGROUP);
}
__device__ __forceinline__ void pollGE(int* f, int target) {
  while (ldAcq(f) < target) {}
}
__device__ __forceinline__ void sigRel(int* f, int v) {
  __hip_atomic_store(f, v, __ATOMIC_RELAXED, __HIP_MEMORY_SCOPE_WORKGROUP);
}

// one softmax term: energies over 64 attention lanes, P = Wh.nr per G-lane.
__device__ __forceinline__ void combBlock(const float4 A0, const float4 A1, const float4 A2,
                                          const float4 A3, float nsv,
                                          const float (&Wa)[16], float ba, float va,
                                          const float (&Wh)[16],
                                          float& S, float& ha, float& Pa) {
  float nr[16] = {A0.x, A0.y, A0.z, A0.w, A1.x, A1.y, A1.z, A1.w,
                  A2.x, A2.y, A2.z, A2.w, A3.x, A3.y, A3.z, A3.w};
  float u = dot16i(Wa, nr, ba);
  float P = dot16r(Wh, nr);
  float pe = va * tanh_p(u);
  float r = rowsum16(pe);
  float e = (rdlane(r, 0) + rdlane(r, 16)) + (rdlane(r, 32) + rdlane(r, 48));
  float w = exp2_(e);
  S += w; ha = fmaf(w, nsv, ha); Pa = fmaf(w, P, Pa);
}

// ---------------- Phase 1: gi0 GEMM (permuted + gate-prescaled output) ----------------
__global__ __launch_bounds__(256) void gi0_gemm(const float* __restrict__ X,
                                                const float* __restrict__ W,
                                                const float* __restrict__ bias) {
  __shared__ float xs[64][132];
  __shared__ float ws[48][132];
  const int tid = threadIdx.x;
  const int t0 = blockIdx.x * 64;
  const int tg = tid & 15;
  const int tt = tid >> 4;
  float acc[4][3];
#pragma unroll
  for (int u = 0; u < 4; ++u)
#pragma unroll
    for (int v = 0; v < 3; ++v) acc[u][v] = 0.f;

  for (int k0 = 0; k0 < FF; k0 += 128) {
#pragma unroll
    for (int i = 0; i < 32; ++i) {
      int e = tid + 256 * i; int r = e >> 7, c = e & 127;
      xs[r][c] = X[(size_t)(t0 + r) * FF + k0 + c];
    }
#pragma unroll
    for (int i = 0; i < 24; ++i) {
      int e = tid + 256 * i; int r = e >> 7, c = e & 127;
      ws[r][c] = W[(size_t)r * FF + k0 + c];
    }
    __syncthreads();
#pragma unroll 8
    for (int c = 0; c < 128; ++c) {
      float x0 = xs[tt][c], x1 = xs[tt + 16][c], x2 = xs[tt + 32][c], x3 = xs[tt + 48][c];
      float w0 = ws[tg][c], w1 = ws[tg + 16][c], w2 = ws[tg + 32][c];
      acc[0][0] += x0 * w0; acc[0][1] += x0 * w1; acc[0][2] += x0 * w2;
      acc[1][0] += x1 * w0; acc[1][1] += x1 * w1; acc[1][2] += x1 * w2;
      acc[2][0] += x2 * w0; acc[2][1] += x2 * w1; acc[2][2] += x2 * w2;
      acc[3][0] += x3 * w0; acc[3][1] += x3 * w1; acc[3][2] += x3 * w2;
    }
    __syncthreads();
  }
  const float gsc3[3] = {-LOG2E, -LOG2E, 2.f * LOG2E};
#pragma unroll
  for (int u = 0; u < 4; ++u)
#pragma unroll
    for (int v = 0; v < 3; ++v)
      g_gi0p[(size_t)(t0 + tt + 16 * u) * 64 + tg * 4 + v] =
          (acc[u][v] + bias[tg + 16 * v]) * gsc3[v];
}

// ---------------- Phase 2: barrier-free sequential scan ----------------
__global__ __launch_bounds__(512, 1) void fbrnn_scan(
    const float* __restrict__ h0,
    const float* __restrict__ Whh0, const float* __restrict__ bhh0,
    const float* __restrict__ Wih, const float* __restrict__ Whh,
    const float* __restrict__ bih, const float* __restrict__ bhh,
    const float* __restrict__ Wa, const float* __restrict__ ba,
    const float* __restrict__ va,
    const float* __restrict__ fc1w, const float* __restrict__ fc1b,
    const float* __restrict__ fc2w, const float* __restrict__ fc2b,
    float* __restrict__ out) {
  __shared__ __align__(16) float nsS[2 * LL * NSR];   // stamped ns rows
  __shared__ __align__(16) float nsOut[256 * NSR];    // stamped ns5 ring (fc)
  __shared__ __align__(16) float4 recS[5 * 64];       // rows 2..4: {gh, h-1, stamp, pad}
  __shared__ __align__(16) float4 partS[12 * 64];     // {S, ha, Pa, stamp}
  __shared__ __align__(16) float chunkS[2][CHUNK * 64];
  __shared__ int flagChunk;   // w4: c+1 after chunk c staged
  __shared__ int flagOut;     // w4: t+1 after out[t] stored

  const int tid = threadIdx.x;
  const int wv = tid >> 6;
  const int lane = tid & 63;
  const int qg = lane & 3;
  const int kk = lane >> 2;
  const int gate = (qg < 3 ? qg : 2);
  const int G = gate * 16 + kk;
  const float gsc = (gate == 2) ? 2.f * LOG2E : -LOG2E;

  const bool isChain = (wv == 0);
  const bool isW4 = (wv == 4);

  // ---- per-role register weights (prescaled; bih folded into gh bases) ----
  float WBih[5][16];
  float WB5[16];  float bhh5R = 0.f;
  float Wa0R[16], Wh0R[16], Wa1R[16], Wh1R[16];
  float ba0R = 0.f, va0R = 0.f, bb0 = 0.f;
  float ba1R = 0.f, va1R = 0.f, bb1 = 0.f;
  float WaA[16], WhA[16]; float baA = 0.f, vaA = 0.f;
  float WaB[16], WhB[16]; float baB = 0.f, vaB = 0.f;
  float WaC[16], WhC[16]; float baC = 0.f, vaC = 0.f;
  float WaT[16], WhT[16]; float baT = 0.f, vaT = 0.f, bhT = 0.f;
  float fc1R[16]; float fb1 = 0.f, fw2 = 0.f, fb2 = 0.f;

#define LOADROW(R, WaX, baX, vaX, WhX) do {                                      \
    _Pragma("unroll") for (int k = 0; k < 16; ++k)                               \
      WaX[k] = Wa[((R) * 16 + k) * 64 + lane] * (2.f * LOG2E);                   \
    baX = ba[(R) * 64 + lane] * (2.f * LOG2E);                                   \
    vaX = va[(R) * 64 + lane] * LOG2E;                                           \
    { const float* ws_ = ((R) == 0) ? (Whh0 + G * 16)                            \
                                    : (Whh + (((R) - 1) * GG + G) * 16);         \
      _Pragma("unroll") for (int k = 0; k < 16; ++k) WhX[k] = ws_[k] * gsc; }    \
  } while (0)
#define LOADBH(R, bhX) do {                                                      \
    bhX = (((R) == 0) ? bhh0[G]                                                  \
                      : (bhh[((R) - 1) * GG + G] + bih[((R) - 1) * GG + G])) *   \
          gsc;                                                                   \
  } while (0)

  if (isChain) {
#pragma unroll
    for (int l = 0; l < 5; ++l)
#pragma unroll
      for (int k = 0; k < 16; ++k) WBih[l][k] = Wih[((l * GG) + G) * 16 + k] * gsc;
#pragma unroll
    for (int k = 0; k < 16; ++k) WB5[k] = Whh[(4 * GG + G) * 16 + k] * gsc;
    bhh5R = (bhh[4 * GG + G] + bih[4 * GG + G]) * gsc;
    LOADROW(0, Wa0R, ba0R, va0R, Wh0R); LOADBH(0, bb0);
    LOADROW(1, Wa1R, ba1R, va1R, Wh1R); LOADBH(1, bb1);
  } else if (isW4) {
    const int m = lane & 31;
#pragma unroll
    for (int k = 0; k < 16; ++k) fc1R[k] = fc1w[m * 16 + k];
    fb1 = fc1b[m]; fw2 = fc2w[m]; fb2 = fc2b[0];
  } else if (wv == 1) {
    LOADROW(0, WaA, baA, vaA, WhA);
    LOADROW(2, WaB, baB, vaB, WhB);
  } else if (wv == 2) {
    LOADROW(0, WaA, baA, vaA, WhA);
    LOADROW(3, WaT, baT, vaT, WhT); LOADBH(3, bhT);
  } else if (wv == 3) {
    LOADROW(1, WaA, baA, vaA, WhA);
    LOADROW(4, WaT, baT, vaT, WhT); LOADBH(4, bhT);
  } else if (wv == 5) {
    LOADROW(0, WaA, baA, vaA, WhA);
    LOADROW(1, WaB, baB, vaB, WhB);
    LOADROW(2, WaT, baT, vaT, WhT); LOADBH(2, bhT);
  } else if (wv == 6) {
    LOADROW(1, WaA, baA, vaA, WhA);
    LOADROW(2, WaB, baB, vaB, WhB);
    LOADROW(3, WaC, baC, vaC, WhC);
  } else {  // wv == 7
    LOADROW(2, WaA, baA, vaA, WhA);
    LOADROW(3, WaB, baB, vaB, WhB);
    LOADROW(4, WaC, baC, vaC, WhC);
  }

  // ---- init: stamps, flags, recs, chain state, chunk0 + prefetch ----
  if (tid == 0) { flagChunk = 1; flagOut = 0; }
  for (int i = tid; i < 2 * LL; i += 512) ((int*)nsS)[i * NSR + 16] = 0;
  for (int i = tid; i < 256; i += 512) ((int*)nsOut)[i * NSR + 16] = 0;
  if (wv == 6) {
#pragma unroll
    for (int s = 0; s < 12; ++s)
      partS[s * 64 + lane] = make_float4(0.f, 0.f, 0.f, __int_as_float(0));
  }

  float hv0m = 0.f, gh0n = 0.f, hv1m = 0.f, gh1n = 0.f;
  float hv5m = 0.f, gh5reg = 0.f;
  if (isChain) {
    float hr[16];
#pragma unroll
    for (int k = 0; k < 16; ++k) hr[k] = h0[5 * 16 + k];
    hv5m = h0[5 * 16 + kk] - 1.f;
    gh5reg = dot16i(WB5, hr, bhh5R);
#pragma unroll
    for (int k = 0; k < 16; ++k) hr[k] = h0[0 * 16 + k];
    hv0m = h0[0 * 16 + kk] - 1.f;
    gh0n = dot16i(Wh0R, hr, bb0);
#pragma unroll
    for (int k = 0; k < 16; ++k) hr[k] = h0[1 * 16 + k];
    hv1m = h0[1 * 16 + kk] - 1.f;
    gh1n = dot16i(Wh1R, hr, bb1);
  }
  const int tailRow = (wv == 5) ? 2 : (wv == 2) ? 3 : (wv == 3) ? 4 : -1;
  if (tailRow >= 0) {
    float hr[16];
#pragma unroll
    for (int k = 0; k < 16; ++k) hr[k] = h0[tailRow * 16 + k];
    float4 rr;
    rr.x = dot16i(WhT, hr, bhT);
    rr.y = h0[tailRow * 16 + kk] - 1.f;
    rr.z = __int_as_float(0); rr.w = 0.f;
    recS[tailRow * 64 + lane] = rr;
  }

  float4 pf0, pf1, pf2, pf3, pf4, pf5, pf6, pf7;
  float4 pf8, pf9, pfA, pfB, pfC, pfD, pfE, pfF;
  if (isW4) {
    const float4* src = (const float4*)g_gi0p;
    float4* dst = (float4*)(&chunkS[0][0]);
#pragma unroll
    for (int q = 0; q < 16; ++q) dst[q * 64 + lane] = src[q * 64 + lane];
    const float4* s1 = (const float4*)(g_gi0p + ((size_t)1 << 12));
    pf0 = s1[0 * 64 + lane]; pf1 = s1[1 * 64 + lane]; pf2 = s1[2 * 64 + lane];
    pf3 = s1[3 * 64 + lane]; pf4 = s1[4 * 64 + lane]; pf5 = s1[5 * 64 + lane];
    pf6 = s1[6 * 64 + lane]; pf7 = s1[7 * 64 + lane]; pf8 = s1[8 * 64 + lane];
    pf9 = s1[9 * 64 + lane]; pfA = s1[10 * 64 + lane]; pfB = s1[11 * 64 + lane];
    pfC = s1[12 * 64 + lane]; pfD = s1[13 * 64 + lane]; pfE = s1[14 * 64 + lane];
    pfF = s1[15 * 64 + lane];
  }
  __syncthreads();  // the only barrier

// stamped ns-row read + accumulate one term (single LDS round trip when fresh)
#define SBLOCK(J, WaX, baX, vaX, WhX, Sx, hax, Pax) do {                          \
    float* base_ = &nsS[(nb * LL + (J)) * NSR];                                   \
    float4 A0_, A1_, A2_, A3_; float nsv_;                                        \
    for (;;) {                                                                    \
      int st_ = ldRlx((int*)(base_ + 16));                                        \
      MEMBAR();                                                                   \
      A0_ = ((const float4*)base_)[0]; A1_ = ((const float4*)base_)[1];           \
      A2_ = ((const float4*)base_)[2]; A3_ = ((const float4*)base_)[3];           \
      nsv_ = base_[kk];                                                           \
      MEMBAR();                                                                   \
      if (st_ >= tgt) break;                                                      \
    }                                                                             \
    combBlock(A0_, A1_, A2_, A3_, nsv_, WaX, baX, vaX, WhX, Sx, hax, Pax);        \
  } while (0)

#define POSTP(SLOT, Sx, hax, Pax) do {                                            \
    MEMBAR();                                                                     \
    partS[(SLOT) * 64 + lane] = make_float4(Sx, hax, Pax, __int_as_float(tgt));   \
    MEMBAR();                                                                     \
  } while (0)

  // ================= w4: streamer + fc head =================
  if (isW4) {
    int cNext = 1;
#pragma unroll 1
    for (int t = 0; t < TT; ++t) {
      const int tgt = t + 1;
      float* nb_ = nsOut + (t & 255) * NSR;
      float4 a0, a1, a2, a3;
      for (;;) {
        int st = ldRlx((int*)(nb_ + 16));
        MEMBAR();
        a0 = ((const float4*)nb_)[0]; a1 = ((const float4*)nb_)[1];
        a2 = ((const float4*)nb_)[2]; a3 = ((const float4*)nb_)[3];
        MEMBAR();
        if (st >= tgt) break;
      }
      float nr[16] = {a0.x, a0.y, a0.z, a0.w, a1.x, a1.y, a1.z, a1.w,
                      a2.x, a2.y, a2.z, a2.w, a3.x, a3.y, a3.z, a3.w};
      float y = dot16i(fc1R, nr, fb1);
      float p = rowsum16(y * fw2);
      float o = rdlane(p, 0) + rdlane(p, 16) + fb2;
      if (lane == 0) out[t] = o;
      MEMBAR();
      sigRel(&flagOut, tgt);
      if ((t & 63) == 48 && cNext < 256) {
        float4* dst = (float4*)(&chunkS[cNext & 1][0]);
        dst[0 * 64 + lane] = pf0;  dst[1 * 64 + lane] = pf1;
        dst[2 * 64 + lane] = pf2;  dst[3 * 64 + lane] = pf3;
        dst[4 * 64 + lane] = pf4;  dst[5 * 64 + lane] = pf5;
        dst[6 * 64 + lane] = pf6;  dst[7 * 64 + lane] = pf7;
        dst[8 * 64 + lane] = pf8;  dst[9 * 64 + lane] = pf9;
        dst[10 * 64 + lane] = pfA; dst[11 * 64 + lane] = pfB;
        dst[12 * 64 + lane] = pfC; dst[13 * 64 + lane] = pfD;
        dst[14 * 64 + lane] = pfE; dst[15 * 64 + lane] = pfF;
        MEMBAR();
        sigRel(&flagChunk, cNext + 1);
        ++cNext;
        if (cNext < 256) {
          const float4* s1 = (const float4*)(g_gi0p + ((size_t)cNext << 12));
          pf0 = s1[0 * 64 + lane]; pf1 = s1[1 * 64 + lane]; pf2 = s1[2 * 64 + lane];
          pf3 = s1[3 * 64 + lane]; pf4 = s1[4 * 64 + lane]; pf5 = s1[5 * 64 + lane];
          pf6 = s1[6 * 64 + lane]; pf7 = s1[7 * 64 + lane]; pf8 = s1[8 * 64 + lane];
          pf9 = s1[9 * 64 + lane]; pfA = s1[10 * 64 + lane]; pfB = s1[11 * 64 + lane];
          pfC = s1[12 * 64 + lane]; pfD = s1[13 * 64 + lane]; pfE = s1[14 * 64 + lane];
          pfF = s1[15 * 64 + lane];
        }
      }
    }
    return;
  }

  // ================= combine / partial waves =================
  if (!isChain) {
    if (wv == 1) {
#pragma unroll 1
      for (int t = 0; t < TT; ++t) {
        const int nb = t & 1; const int tgt = t + 1;
        float S = 0.f, ha = 0.f, Pa = 0.f;
        SBLOCK(0, WaA, baA, vaA, WhA, S, ha, Pa);
        SBLOCK(3, WaA, baA, vaA, WhA, S, ha, Pa);
        POSTP(0, S, ha, Pa);
        S = 0.f; ha = 0.f; Pa = 0.f;
        SBLOCK(4, WaB, baB, vaB, WhB, S, ha, Pa);
        POSTP(8, S, ha, Pa);
      }
    } else if (wv == 2) {
#pragma unroll 1
      for (int t = 0; t < TT; ++t) {
        const int nb = t & 1; const int tgt = t + 1;
        float S = 0.f, ha = 0.f, Pa = 0.f;
        SBLOCK(1, WaA, baA, vaA, WhA, S, ha, Pa);
        SBLOCK(4, WaA, baA, vaA, WhA, S, ha, Pa);
        POSTP(1, S, ha, Pa);
        S = 0.f; ha = 0.f; Pa = 0.f;
        SBLOCK(5, WaT, baT, vaT, WhT, S, ha, Pa);
        float4 m0, m1;
        for (;;) {
          MEMBAR();
          m0 = partS[9 * 64 + lane]; m1 = partS[10 * 64 + lane];
          MEMBAR();
          int ok = (__float_as_int(m0.w) >= tgt) & (__float_as_int(m1.w) >= tgt);
          if (__all(ok)) break;
        }
        S += m0.x + m1.x; ha += m0.y + m1.y; Pa += m0.z + m1.z;
        const float inv = rcp_(S);
        float4 rr; rr.x = fmaf(Pa, inv, bhT); rr.y = fmaf(ha, inv, -1.f);
        rr.z = __int_as_float(tgt); rr.w = 0.f;
        MEMBAR();
        recS[3 * 64 + lane] = rr;
        MEMBAR();
      }
    } else if (wv == 3) {
#pragma unroll 1
      for (int t = 0; t < TT; ++t) {
        const int nb = t & 1; const int tgt = t + 1;
        float S = 0.f, ha = 0.f, Pa = 0.f;
        SBLOCK(1, WaA, baA, vaA, WhA, S, ha, Pa);
        SBLOCK(4, WaA, baA, vaA, WhA, S, ha, Pa);
        POSTP(3, S, ha, Pa);
        S = 0.f; ha = 0.f; Pa = 0.f;
        SBLOCK(5, WaT, baT, vaT, WhT, S, ha, Pa);
        float4 m0;
        for (;;) {
          MEMBAR();
          m0 = partS[11 * 64 + lane];
          MEMBAR();
          if (__all(__float_as_int(m0.w) >= tgt)) break;
        }
        S += m0.x; ha += m0.y; Pa += m0.z;
        const float inv = rcp_(S);
        float4 rr; rr.x = fmaf(Pa, inv, bhT); rr.y = fmaf(ha, inv, -1.f);
        rr.z = __int_as_float(tgt); rr.w = 0.f;
        MEMBAR();
        recS[4 * 64 + lane] = rr;
        MEMBAR();
      }
    } else if (wv == 5) {
#pragma unroll 1
      for (int t = 0; t < TT; ++t) {
        const int nb = t & 1; const int tgt = t + 1;
        float S = 0.f, ha = 0.f, Pa = 0.f;
        SBLOCK(2, WaA, baA, vaA, WhA, S, ha, Pa);
        POSTP(2, S, ha, Pa);
        S = 0.f; ha = 0.f; Pa = 0.f;
        SBLOCK(3, WaB, baB, vaB, WhB, S, ha, Pa);
        POSTP(5, S, ha, Pa);
        S = 0.f; ha = 0.f; Pa = 0.f;
        SBLOCK(5, WaT, baT, vaT, WhT, S, ha, Pa);
        float4 m0, m1, m2;
        for (;;) {
          MEMBAR();
          m0 = partS[6 * 64 + lane]; m1 = partS[7 * 64 + lane]; m2 = partS[8 * 64 + lane];
          MEMBAR();
          int ok = (__float_as_int(m0.w) >= tgt) & (__float_as_int(m1.w) >= tgt) &
                   (__float_as_int(m2.w) >= tgt);
          if (__all(ok)) break;
        }
        S += m0.x + m1.x + m2.x; ha += m0.y + m1.y + m2.y; Pa += m0.z + m1.z + m2.z;
        const float inv = rcp_(S);
        float4 rr; rr.x = fmaf(Pa, inv, bhT); rr.y = fmaf(ha, inv, -1.f);
        rr.z = __int_as_float(tgt); rr.w = 0.f;
        MEMBAR();
        recS[2 * 64 + lane] = rr;
        MEMBAR();
      }
    } else if (wv == 6) {
#pragma unroll 1
      for (int t = 0; t < TT; ++t) {
        const int nb = t & 1; const int tgt = t + 1;
        float S = 0.f, ha = 0.f, Pa = 0.f;
        SBLOCK(2, WaA, baA, vaA, WhA, S, ha, Pa);
        POSTP(4, S, ha, Pa);
        S = 0.f; ha = 0.f; Pa = 0.f;
        SBLOCK(3, WaB, baB, vaB, WhB, S, ha, Pa);
        POSTP(7, S, ha, Pa);
        S = 0.f; ha = 0.f; Pa = 0.f;
        SBLOCK(4, WaC, baC, vaC, WhC, S, ha, Pa);
        POSTP(10, S, ha, Pa);
      }
    } else {  // wv == 7
#pragma unroll 1
      for (int t = 0; t < TT; ++t) {
        const int nb = t & 1; const int tgt = t + 1;
        float S = 0.f, ha = 0.f, Pa = 0.f;
        SBLOCK(2, WaA, baA, vaA, WhA, S, ha, Pa);
        POSTP(6, S, ha, Pa);
        S = 0.f; ha = 0.f; Pa = 0.f;
        SBLOCK(3, WaB, baB, vaB, WhB, S, ha, Pa);
        POSTP(9, S, ha, Pa);
        S = 0.f; ha = 0.f; Pa = 0.f;
        SBLOCK(4, WaC, baC, vaC, WhC, S, ha, Pa);
        POSTP(11, S, ha, Pa);
      }
    }
    return;
  }

  // ================= GRU chain (w0) =================
  float gnext = chunkS[0][lane];
  float ns_sg[16];
#pragma unroll 1
  for (int t = 0; t < TT; ++t) {
    const int wb = t & 1;

    float ghv[6], hvm1[6];
    ghv[0] = gh0n; hvm1[0] = hv0m;
    ghv[1] = gh1n; hvm1[1] = hv1m;
    ghv[5] = gh5reg; hvm1[5] = hv5m;
    float4 r2, r3, r4;
    float gpre = 0.f;
    float gi0v = gnext;
    float ns = 0.f;
#pragma unroll
    for (int l = 0; l < 6; ++l) {
      if (l == 2) {
        if (!((__float_as_int(r2.z) >= t) & (__float_as_int(r3.z) >= t) &
              (__float_as_int(r4.z) >= t))) {
          do {
            MEMBAR();
            r2 = recS[2 * 64 + lane]; r3 = recS[3 * 64 + lane]; r4 = recS[4 * 64 + lane];
            MEMBAR();
          } while (!((__float_as_int(r2.z) >= t) & (__float_as_int(r3.z) >= t) &
                     (__float_as_int(r4.z) >= t)));
        }
        ghv[2] = r2.x; hvm1[2] = r2.y;
        ghv[3] = r3.x; hvm1[3] = r3.y;
        ghv[4] = r4.x; hvm1[4] = r4.y;
      }
      const float gh_g = ghv[l];
      const float s = (l == 0) ? (gi0v + gh_g) : dot16i(WBih[l - 1], ns_sg, gh_g);
      const float sg = sig_n(s);                    // r at qg=0, z at qg=1
      const float smg = s - gh_g;                   // scaled i_n at qg=2
      const float sr = qbcast<0>(sg);
      const float sz = qbcast<1>(sg);
      const float nb2 = fmaf(2.f, sz, -2.f);        // -2*(1-z), in tanh shadow
      const float apb = fmaf(sz, hvm1[l], 1.f);     // z*h + (1-z)
      const float E = exp2_(fmaf(sr, gh_g, smg));
      const float R = rcp_(E + 1.f);
      ns = fmaf(nb2, R, apb);                       // valid at qg=2 lanes
      if (qg == 2) {
        nsS[(wb * LL + l) * NSR + kk] = ns;
        if (l == 5) nsOut[(t & 255) * NSR + kk] = ns;
      }
      MEMBAR();
      if (qg == 2 && kk == 0) {  // lane 2 stamps (after data, in-order DS)
        sigRel((int*)&nsS[(wb * LL + l) * NSR + 16], t + 1);
        if (l == 5) sigRel((int*)&nsOut[(t & 255) * NSR + 16], t + 1);
      }
      MEMBAR();
#pragma unroll
      for (int k = 0; k < 16; ++k) ns_sg[k] = rdlane(ns, 4 * k + 2);
      if (l == 0) {
        // slack region: housekeeping + prefetch + rec spec reads
        if ((t & 63) == 63) {
          const int cn = (t + 1) >> 6;
          if (cn < 256) pollGE(&flagChunk, cn + 1);
        }
        if ((t & 63) == 32) pollGE(&flagOut, t - 64);
        gpre = chunkS[((t + 1) >> 6) & 1][((t + 1) & 63) * 64 + lane];
        MEMBAR();
        r2 = recS[2 * 64 + lane]; r3 = recS[3 * 64 + lane]; r4 = recS[4 * 64 + lane];
        MEMBAR();
      }
    }
    // ---- post-layer-5: row5 state + in-chain row0/row1 tails ----
    MEMBAR();
    float4 q0 = partS[0 * 64 + lane], q1 = partS[1 * 64 + lane], q2 = partS[2 * 64 + lane];
    float4 q3 = partS[3 * 64 + lane], q4 = partS[4 * 64 + lane], q5 = partS[5 * 64 + lane];
    MEMBAR();
    const float hv5n = qbcast<2>(ns);
    gh5reg = dot16i(WB5, ns_sg, bhh5R);
    float u0 = dot16i(Wa0R, ns_sg, ba0R);
    float u1 = dot16i(Wa1R, ns_sg, ba1R);
    float P0 = dot16r(Wh0R, ns_sg);
    float P1 = dot16r(Wh1R, ns_sg);
    float pe0 = va0R * tanh_p(u0);
    float pe1 = va1R * tanh_p(u1);
    float rs0 = rowsum16(pe0);
    float rs1 = rowsum16(pe1);
    float e0 = (rdlane(rs0, 0) + rdlane(rs0, 16)) + (rdlane(rs0, 32) + rdlane(rs0, 48));
    float e1 = (rdlane(rs1, 0) + rdlane(rs1, 16)) + (rdlane(rs1, 32) + rdlane(rs1, 48));
    float wj0 = exp2_(e0), wj1 = exp2_(e1);
    const int tp = t + 1;
    if (!((__float_as_int(q0.w) >= tp) & (__float_as_int(q1.w) >= tp) &
          (__float_as_int(q2.w) >= tp) & (__float_as_int(q3.w) >= tp) &
          (__float_as_int(q4.w) >= tp) & (__float_as_int(q5.w) >= tp))) {
      do {
        MEMBAR();
        q0 = partS[0 * 64 + lane]; q1 = partS[1 * 64 + lane]; q2 = partS[2 * 64 + lane];
        q3 = partS[3 * 64 + lane]; q4 = partS[4 * 64 + lane]; q5 = partS[5 * 64 + lane];
        MEMBAR();
      } while (!((__float_as_int(q0.w) >= tp) & (__float_as_int(q1.w) >= tp) &
                 (__float_as_int(q2.w) >= tp) & (__float_as_int(q3.w) >= tp) &
                 (__float_as_int(q4.w) >= tp) & (__float_as_int(q5.w) >= tp)));
    }
    float S0 = q0.x + q1.x + q2.x + wj0;
    float hT0 = q0.y + q1.y + q2.y + wj0 * hv5n;
    float PT0 = q0.z + q1.z + q2.z + wj0 * P0;
    float S1 = q3.x + q4.x + q5.x + wj1;
    float hT1 = q3.y + q4.y + q5.y + wj1 * hv5n;
    float PT1 = q3.z + q4.z + q5.z + wj1 * P1;
    const float inv0 = rcp_(S0);
    const float inv1 = rcp_(S1);
    gh0n = fmaf(PT0, inv0, bb0); hv0m = fmaf(hT0, inv0, -1.f);
    gh1n = fmaf(PT1, inv1, bb1); hv1m = fmaf(hT1, inv1, -1.f);
    hv5m = hv5n - 1.f;
    gnext = gpre;
  }
}

extern "C" void kernel_launch(void* const* d_in, const int* in_sizes, int n_in,
                              void* d_out, int out_size, void* d_ws, size_t ws_size,
                              hipStream_t stream) {
  const float* batch = (const float*)d_in[0];
  const float* h0    = (const float*)d_in[1];
  const float* Wih0  = (const float*)d_in[2];
  const float* Whh0  = (const float*)d_in[3];
  const float* bih0  = (const float*)d_in[4];
  const float* bhh0  = (const float*)d_in[5];
  const float* Wih   = (const float*)d_in[6];
  const float* Whh   = (const float*)d_in[7];
  const float* bih   = (const float*)d_in[8];
  const float* bhh   = (const float*)d_in[9];
  const float* Wa    = (const float*)d_in[10];
  const float* ba    = (const float*)d_in[11];
  const float* va    = (const float*)d_in[12];
  const float* fc1w  = (const float*)d_in[13];
  const float* fc1b  = (const float*)d_in[14];
  const float* fc2w  = (const float*)d_in[15];
  const float* fc2b  = (const float*)d_in[16];
  float* out = (float*)d_out;
  (void)in_sizes; (void)n_in; (void)out_size; (void)d_ws; (void)ws_size;

  gi0_gemm<<<TT / 64, 256, 0, stream>>>(batch, Wih0, bih0);
  fbrnn_scan<<<1, 512, 0, stream>>>(h0, Whh0, bhh0, Wih, Whh, bih, bhh,
                                    Wa, ba, va, fc1w, fc1b, fc2w, fc2b, out);
}

// Round 5
// 27542.999 us; speedup vs baseline: 2.3982x; 2.3982x over previous
//
#include <hip/hip_runtime.h>
#include <cstdint>
#include <cstddef>

// FBRNN: T=16384, F=2048, H=16, A=64, L=6, G=3H=48.
// R13 = R11 structure (verified 22.1ms) + folded ns update + in-chain j3/j4
// blocks for rows 0/1 (computed in the spine's latency bubbles; ns_j already
// in registers, ns_j[kk] via qbcast<2>). R12's wide-read spin reverted: all
// polls spin on a single dword (flagNs/gen5/stamps), data read after.
// Role map:
//   w0 = chain (layers 0-5 + rows0/1 j3,j4 in-shadow + j5 tails + finalize)
//   w4 = gi0 chunk streamer
//   w6 = row0 partial {j0,j1,j2} -> partS[0] + fc head
//   w2 = row1 partial {j1,j2}    -> partS[2]
//   w3 = row2 {j2,j3,j4,j5}+fin -> recS[2]
//   w7 = row3 {j3,j4,j5}+fin    -> recS[3]
//   w5 = row4 {j4,j5}+fin       -> recS[4]
//   w1 = idle

#define TT 16384
#define FF 2048
#define HH 16
#define LL 6
#define GG 48
#define CHUNK 64
#define LOG2E 1.44269504088896340736f

__device__ float g_gi0p[(TT + CHUNK) * 64];

__device__ __forceinline__ float exp2_(float x) { return __builtin_amdgcn_exp2f(x); }
__device__ __forceinline__ float rcp_(float x) { return __builtin_amdgcn_rcpf(x); }
__device__ __forceinline__ float sig_n(float s) { return rcp_(1.f + exp2_(s)); }
__device__ __forceinline__ float tanh_p(float s) { return fmaf(-2.f, rcp_(exp2_(s) + 1.f), 1.f); }

#define MEMBAR() __asm__ __volatile__("" ::: "memory")

__device__ __forceinline__ float rdlane(float v, int l) {
  union { float f; int i; } a, b;
  a.f = v; b.i = __builtin_amdgcn_readlane(a.i, l); return b.f;
}
template <int CTRL>
__device__ __forceinline__ float dppf(float v) {
  union { float f; int i; } a, b;
  a.f = v; b.i = __builtin_amdgcn_mov_dpp(a.i, CTRL, 0xF, 0xF, true); return b.f;
}
template <int Q>
__device__ __forceinline__ float qbcast(float v) { return dppf<Q | (Q << 2) | (Q << 4) | (Q << 6)>(v); }

__device__ __forceinline__ float rowsum16(float v) {
  v += dppf<0xB1>(v);
  v += dppf<0x4E>(v);
  v += dppf<0x141>(v);
  v += dppf<0x140>(v);
  return v;
}
__device__ __forceinline__ float dot16r(const float (&w)[16], const float (&h)[16]) {
  float s0 = w[0] * h[0], s1 = w[1] * h[1], s2 = w[2] * h[2], s3 = w[3] * h[3];
#pragma unroll
  for (int k = 4; k < 16; k += 4) {
    s0 = fmaf(w[k], h[k], s0);       s1 = fmaf(w[k + 1], h[k + 1], s1);
    s2 = fmaf(w[k + 2], h[k + 2], s2); s3 = fmaf(w[k + 3], h[k + 3], s3);
  }
  return (s0 + s1) + (s2 + s3);
}
__device__ __forceinline__ float dot16i(const float (&w)[16], const float (&h)[16], float init) {
  float s0 = fmaf(w[0], h[0], init), s1 = w[1] * h[1], s2 = w[2] * h[2], s3 = w[3] * h[3];
#pragma unroll
  for (int k = 4; k < 16; k += 4) {
    s0 = fmaf(w[k], h[k], s0);       s1 = fmaf(w[k + 1], h[k + 1], s1);
    s2 = fmaf(w[k + 2], h[k + 2], s2); s3 = fmaf(w[k + 3], h[k + 3], s3);
  }
  return (s0 + s1) + (s2 + s3);
}

__device__ __forceinline__ int ldAcq(int* f) {
  return __hip_atomic_load(f, __ATOMIC_ACQUIRE, __HIP_MEMORY_SCOPE_WORKGROUP);
}
__device__ __forceinline__ void pollGE(int* f, int target) {
  while (ldAcq(f) < target) {}
}
__device__ __forceinline__ void waitFlag(int* f, int& cache, int need) {
  if (cache < need) { do { cache = ldAcq(f); } while (cache < need); }
}
// relaxed flag store: LDS ds ops are in-order per wave; MEMBAR() pins compile order.
__device__ __forceinline__ void sigRel(int* f, int v) {
  __hip_atomic_store(f, v, __ATOMIC_RELAXED, __HIP_MEMORY_SCOPE_WORKGROUP);
}

// one softmax term: energies over 64 attention lanes, P = Wh.nr per G-lane.
__device__ __forceinline__ void combBlock(const float4 A0, const float4 A1, const float4 A2,
                                          const float4 A3, float nsv,
                                          const float (&Wa)[16], float ba, float va,
                                          const float (&Wh)[16],
                                          float& S, float& ha, float& Pa) {
  float nr[16] = {A0.x, A0.y, A0.z, A0.w, A1.x, A1.y, A1.z, A1.w,
                  A2.x, A2.y, A2.z, A2.w, A3.x, A3.y, A3.z, A3.w};
  float u = dot16i(Wa, nr, ba);
  float P = dot16r(Wh, nr);
  float pe = va * tanh_p(u);
  float r = rowsum16(pe);
  float e = (rdlane(r, 0) + rdlane(r, 16)) + (rdlane(r, 32) + rdlane(r, 48));
  float w = exp2_(e);
  S += w; ha = fmaf(w, nsv, ha); Pa = fmaf(w, P, Pa);
}

// ---------------- Phase 1: gi0 GEMM (permuted + gate-prescaled output) ----------------
__global__ __launch_bounds__(256) void gi0_gemm(const float* __restrict__ X,
                                                const float* __restrict__ W,
                                                const float* __restrict__ bias) {
  __shared__ float xs[64][132];
  __shared__ float ws[48][132];
  const int tid = threadIdx.x;
  const int t0 = blockIdx.x * 64;
  const int tg = tid & 15;
  const int tt = tid >> 4;
  float acc[4][3];
#pragma unroll
  for (int u = 0; u < 4; ++u)
#pragma unroll
    for (int v = 0; v < 3; ++v) acc[u][v] = 0.f;

  for (int k0 = 0; k0 < FF; k0 += 128) {
#pragma unroll
    for (int i = 0; i < 32; ++i) {
      int e = tid + 256 * i; int r = e >> 7, c = e & 127;
      xs[r][c] = X[(size_t)(t0 + r) * FF + k0 + c];
    }
#pragma unroll
    for (int i = 0; i < 24; ++i) {
      int e = tid + 256 * i; int r = e >> 7, c = e & 127;
      ws[r][c] = W[(size_t)r * FF + k0 + c];
    }
    __syncthreads();
#pragma unroll 8
    for (int c = 0; c < 128; ++c) {
      float x0 = xs[tt][c], x1 = xs[tt + 16][c], x2 = xs[tt + 32][c], x3 = xs[tt + 48][c];
      float w0 = ws[tg][c], w1 = ws[tg + 16][c], w2 = ws[tg + 32][c];
      acc[0][0] += x0 * w0; acc[0][1] += x0 * w1; acc[0][2] += x0 * w2;
      acc[1][0] += x1 * w0; acc[1][1] += x1 * w1; acc[1][2] += x1 * w2;
      acc[2][0] += x2 * w0; acc[2][1] += x2 * w1; acc[2][2] += x2 * w2;
      acc[3][0] += x3 * w0; acc[3][1] += x3 * w1; acc[3][2] += x3 * w2;
    }
    __syncthreads();
  }
  const float gsc3[3] = {-LOG2E, -LOG2E, 2.f * LOG2E};
#pragma unroll
  for (int u = 0; u < 4; ++u)
#pragma unroll
    for (int v = 0; v < 3; ++v)
      g_gi0p[(size_t)(t0 + tt + 16 * u) * 64 + tg * 4 + v] =
          (acc[u][v] + bias[tg + 16 * v]) * gsc3[v];
}

// ---------------- Phase 2: barrier-free sequential scan ----------------
__global__ __launch_bounds__(512, 1) void fbrnn_scan(
    const float* __restrict__ h0,
    const float* __restrict__ Whh0, const float* __restrict__ bhh0,
    const float* __restrict__ Wih, const float* __restrict__ Whh,
    const float* __restrict__ bih, const float* __restrict__ bhh,
    const float* __restrict__ Wa, const float* __restrict__ ba,
    const float* __restrict__ va,
    const float* __restrict__ fc1w, const float* __restrict__ fc1b,
    const float* __restrict__ fc2w, const float* __restrict__ fc2b,
    float* __restrict__ out) {
  __shared__ __align__(16) float nsS[2][LL * HH];     // ns, buf = t&1 (unscaled)
  __shared__ __align__(16) float4 recS[5 * 64];       // rows 2..4: {gh, h-1, stamp, pad}
  __shared__ __align__(16) float4 partS[4 * 64];      // {S, ha, Pa, stamp}
  __shared__ __align__(16) float nsOut[256 * HH];     // ns5 ring for fc (w6)
  __shared__ __align__(16) float chunkS[2][CHUNK * 64];
  __shared__ int flagNs;      // chain: t*8 + l + 1 after ns_l visible
  __shared__ int flagChunk;   // streamer: c+1 after chunk c staged
  __shared__ int flagOut;     // w6: t+1 after out[t] stored
  __shared__ int gen5[2];     // chain: t+1 after ns5 of step t stored in nsS[t&1]

  const int tid = threadIdx.x;
  const int wv = tid >> 6;
  const int lane = tid & 63;
  const int qg = lane & 3;
  const int kk = lane >> 2;
  const int gate = (qg < 3 ? qg : 2);
  const int G = gate * 16 + kk;
  const float gsc = (gate == 2) ? 2.f * LOG2E : -LOG2E;

  const bool isChain = (wv == 0);
  const bool isStream = (wv == 4);
  const bool isFc = (wv == 6);
  const bool isIdle = (wv == 1);
  // helper (partial) row / primary (tail) row per wave
  const int hRow = (wv == 6) ? 0 : (wv == 2) ? 1 : -1;
  const int pRow = (wv == 3) ? 2 : (wv == 7) ? 3 : (wv == 5) ? 4 : -1;
  const int pSlot = (wv == 6) ? 0 : (wv == 2) ? 2 : -1;

  // ---- per-role register weights (prescaled; bih folded into gh bases) ----
  float WBih[5][16];
  float WB5[16];  float bhh5R = 0.f;
  float Wa0R[16], Wh0R[16], Wa1R[16], Wh1R[16];
  float ba0R = 0.f, va0R = 0.f, bb0 = 0.f;
  float ba1R = 0.f, va1R = 0.f, bb1 = 0.f;
  float WaP[16], WhP[16];
  float baP = 0.f, vaP = 0.f, bhhP = 0.f;
  float WaH[16], WhH[16];
  float baH = 0.f, vaH = 0.f;
  float fc1R[16];
  float fb1 = 0.f, fw2 = 0.f, fb2 = 0.f;

  if (isChain) {
#pragma unroll
    for (int l = 0; l < 5; ++l)
#pragma unroll
      for (int k = 0; k < 16; ++k) WBih[l][k] = Wih[((l * GG) + G) * 16 + k] * gsc;
#pragma unroll
    for (int k = 0; k < 16; ++k) WB5[k] = Whh[(4 * GG + G) * 16 + k] * gsc;
    bhh5R = (bhh[4 * GG + G] + bih[4 * GG + G]) * gsc;
#pragma unroll
    for (int k = 0; k < 16; ++k) {
      Wa0R[k] = Wa[(0 * 16 + k) * 64 + lane] * (2.f * LOG2E);
      Wa1R[k] = Wa[(1 * 16 + k) * 64 + lane] * (2.f * LOG2E);
      Wh0R[k] = Whh0[G * 16 + k] * gsc;
      Wh1R[k] = Whh[(0 * GG + G) * 16 + k] * gsc;
    }
    ba0R = ba[0 * 64 + lane] * (2.f * LOG2E); va0R = va[0 * 64 + lane] * LOG2E;
    ba1R = ba[1 * 64 + lane] * (2.f * LOG2E); va1R = va[1 * 64 + lane] * LOG2E;
    bb0 = bhh0[G] * gsc;
    bb1 = (bhh[0 * GG + G] + bih[0 * GG + G]) * gsc;
  }
  if (pRow >= 0) {
#pragma unroll
    for (int k = 0; k < 16; ++k) WaP[k] = Wa[(pRow * 16 + k) * 64 + lane] * (2.f * LOG2E);
    baP = ba[pRow * 64 + lane] * (2.f * LOG2E);
    vaP = va[pRow * 64 + lane] * LOG2E;
    const float* ws = Whh + ((pRow - 1) * GG + G) * 16;
#pragma unroll
    for (int k = 0; k < 16; ++k) WhP[k] = ws[k] * gsc;
    bhhP = (bhh[(pRow - 1) * GG + G] + bih[(pRow - 1) * GG + G]) * gsc;
  }
  if (hRow >= 0) {
#pragma unroll
    for (int k = 0; k < 16; ++k) WaH[k] = Wa[(hRow * 16 + k) * 64 + lane] * (2.f * LOG2E);
    baH = ba[hRow * 64 + lane] * (2.f * LOG2E);
    vaH = va[hRow * 64 + lane] * LOG2E;
    const float* ws = (hRow == 0) ? (Whh0 + G * 16) : (Whh + ((hRow - 1) * GG + G) * 16);
#pragma unroll
    for (int k = 0; k < 16; ++k) WhH[k] = ws[k] * gsc;
  }
  if (isFc) {
    const int m = lane & 31;
#pragma unroll
    for (int k = 0; k < 16; ++k) fc1R[k] = fc1w[m * 16 + k];
    fb1 = fc1b[m]; fw2 = fc2w[m]; fb2 = fc2b[0];
  }

  if (tid == 0) { flagNs = 0; flagChunk = 1; flagOut = 0; gen5[0] = 0; gen5[1] = 0; }

  // chain state registers (hv* carried as h-1)
  float hv5m = 0.f, gh5reg = 0.f;
  float gh0n = 0.f, hv0m = 0.f, gh1n = 0.f, hv1m = 0.f;
  if (isChain) {
    float hr[16];
#pragma unroll
    for (int k = 0; k < 16; ++k) hr[k] = h0[5 * 16 + k];
    hv5m = h0[5 * 16 + kk] - 1.f;
    gh5reg = dot16i(WB5, hr, bhh5R);
#pragma unroll
    for (int k = 0; k < 16; ++k) hr[k] = h0[0 * 16 + k];
    hv0m = h0[0 * 16 + kk] - 1.f;
    gh0n = dot16i(Wh0R, hr, bb0);
#pragma unroll
    for (int k = 0; k < 16; ++k) hr[k] = h0[1 * 16 + k];
    hv1m = h0[1 * 16 + kk] - 1.f;
    gh1n = dot16i(Wh1R, hr, bb1);
  } else if (pRow >= 0) {
    float hr[16];
#pragma unroll
    for (int k = 0; k < 16; ++k) hr[k] = h0[pRow * 16 + k];
    float4 rr;
    rr.x = dot16i(WhP, hr, bhhP);
    rr.y = h0[pRow * 16 + kk] - 1.f;
    rr.z = __int_as_float(0);
    rr.w = 0.f;
    recS[pRow * 64 + lane] = rr;
  }
  if (isStream) {
    const float4* src = (const float4*)g_gi0p;
    float4* dst = (float4*)(&chunkS[0][0]);
#pragma unroll
    for (int q = 0; q < 16; ++q) dst[q * 64 + lane] = src[q * 64 + lane];
  }
  if (pSlot >= 0) partS[pSlot * 64 + lane] = make_float4(0.f, 0.f, 0.f, __int_as_float(0));
  __syncthreads();  // the only barrier

  if (isIdle) return;

// early combine block: wait flag (single-dword spin), read nsS row J, accumulate
#define EBLOCK(J, WaX, baX, vaX, WhX, Sx, hax, Pax) do {                          \
    waitFlag(&flagNs, fcache, t * 8 + (J) + 1);                                   \
    const float4* np_ = (const float4*)&nsS[nb][(J) * 16];                        \
    float4 A0_ = np_[0], A1_ = np_[1], A2_ = np_[2], A3_ = np_[3];                \
    float nsv_ = nsS[nb][(J) * 16 + kk];                                          \
    combBlock(A0_, A1_, A2_, A3_, nsv_, WaX, baX, vaX, WhX, Sx, hax, Pax);        \
  } while (0)

// j=5 tail: gen5 poll (data read in-iteration), accumulate, finalize, write rec
#define TAILFIN(ROW, Sv, hav, Pav) do {                                           \
    float4 A0, A1, A2, A3; float nsv5;                                            \
    for (;;) {                                                                    \
      int g5 = ldAcq(&gen5[nb]);                                                  \
      MEMBAR();                                                                   \
      const float4* np = (const float4*)&nsS[nb][5 * 16];                         \
      A0 = np[0]; A1 = np[1]; A2 = np[2]; A3 = np[3];                             \
      nsv5 = nsS[nb][5 * 16 + kk];                                                \
      MEMBAR();                                                                   \
      if (g5 >= tgt) break;                                                       \
    }                                                                             \
    combBlock(A0, A1, A2, A3, nsv5, WaP, baP, vaP, WhP, Sv, hav, Pav);            \
    const float inv_ = rcp_(Sv);                                                  \
    float4 rr_; rr_.x = fmaf(Pav, inv_, bhhP); rr_.y = fmaf(hav, inv_, -1.f);     \
    rr_.z = __int_as_float(tgt); rr_.w = 0.f;                                     \
    recS[(ROW) * 64 + lane] = rr_;                                                \
  } while (0)

  // ================= streamer (w4) =================
  if (isStream) {
#pragma unroll 1
    for (int c = 1; c < 256; ++c) {
      if (c >= 2) pollGE(&flagNs, ((c - 1) * 64 - 1) * 8 + 1);
      const float4* src = (const float4*)(g_gi0p + ((size_t)c << 12));
      float4* dst = (float4*)(&chunkS[c & 1][0]);
#pragma unroll
      for (int q = 0; q < 16; ++q) dst[q * 64 + lane] = src[q * 64 + lane];
      MEMBAR();
      sigRel(&flagChunk, c + 1);
    }
    return;
  }

  // ================= w6: row0 partial {j0,j1,j2} + fc head =================
  if (isFc) {
    int fcache = 0;
#pragma unroll 1
    for (int t = 0; t < TT; ++t) {
      const int nb = t & 1;
      float Sh = 0.f, hah = 0.f, Pah = 0.f;
      EBLOCK(0, WaH, baH, vaH, WhH, Sh, hah, Pah);
      EBLOCK(1, WaH, baH, vaH, WhH, Sh, hah, Pah);
      EBLOCK(2, WaH, baH, vaH, WhH, Sh, hah, Pah);
      MEMBAR();
      partS[0 * 64 + lane] = make_float4(Sh, hah, Pah, __int_as_float(t + 1));
      MEMBAR();
      // fc tail
      waitFlag(&flagNs, fcache, t * 8 + 6);
      const float4* np = (const float4*)(nsOut + (t & 255) * 16);
      float4 a0 = np[0], a1 = np[1], a2 = np[2], a3 = np[3];
      float nr[16] = {a0.x, a0.y, a0.z, a0.w, a1.x, a1.y, a1.z, a1.w,
                      a2.x, a2.y, a2.z, a2.w, a3.x, a3.y, a3.z, a3.w};
      float y = dot16i(fc1R, nr, fb1);
      float p = rowsum16(y * fw2);
      float o = rdlane(p, 0) + rdlane(p, 16) + fb2;
      if (lane == 0) out[t] = o;
      MEMBAR();
      sigRel(&flagOut, t + 1);
    }
    return;
  }

  // ================= combine / partial waves =================
  if (!isChain) {
    int fcache = 0;
    if (wv == 2) {         // row1 partial {j1,j2}
#pragma unroll 1
      for (int t = 0; t < TT; ++t) {
        const int nb = t & 1;
        float Sh = 0.f, hah = 0.f, Pah = 0.f;
        EBLOCK(1, WaH, baH, vaH, WhH, Sh, hah, Pah);
        EBLOCK(2, WaH, baH, vaH, WhH, Sh, hah, Pah);
        MEMBAR();
        partS[2 * 64 + lane] = make_float4(Sh, hah, Pah, __int_as_float(t + 1));
        MEMBAR();
      }
    } else if (wv == 3) {  // row2 {j2,j3,j4,j5}+fin
#pragma unroll 1
      for (int t = 0; t < TT; ++t) {
        const int nb = t & 1;
        const int tgt = t + 1;
        float S = 0.f, ha = 0.f, Pa = 0.f;
        EBLOCK(2, WaP, baP, vaP, WhP, S, ha, Pa);
        EBLOCK(3, WaP, baP, vaP, WhP, S, ha, Pa);
        EBLOCK(4, WaP, baP, vaP, WhP, S, ha, Pa);
        TAILFIN(2, S, ha, Pa);
      }
    } else if (wv == 7) {  // row3 {j3,j4,j5}+fin
#pragma unroll 1
      for (int t = 0; t < TT; ++t) {
        const int nb = t & 1;
        const int tgt = t + 1;
        float S = 0.f, ha = 0.f, Pa = 0.f;
        EBLOCK(3, WaP, baP, vaP, WhP, S, ha, Pa);
        EBLOCK(4, WaP, baP, vaP, WhP, S, ha, Pa);
        TAILFIN(3, S, ha, Pa);
      }
    } else {               // wv == 5: row4 {j4,j5}+fin
#pragma unroll 1
      for (int t = 0; t < TT; ++t) {
        const int nb = t & 1;
        const int tgt = t + 1;
        float S = 0.f, ha = 0.f, Pa = 0.f;
        EBLOCK(4, WaP, baP, vaP, WhP, S, ha, Pa);
        TAILFIN(4, S, ha, Pa);
      }
    }
    return;
  }

  // ================= GRU chain (w0) =================
  float gnext = chunkS[0][lane];
  float ns_sg[16];
#pragma unroll 1
  for (int t = 0; t < TT; ++t) {
    const int wb = t & 1;

    float ghv[6], hvm1[6];
    ghv[0] = gh0n; hvm1[0] = hv0m;
    ghv[1] = gh1n; hvm1[1] = hv1m;
    ghv[5] = gh5reg; hvm1[5] = hv5m;
    float4 r2, r3, r4;
    float gpre = 0.f;
    float gi0v = gnext;
    float ns = 0.f;
    // in-chain j3/j4 accumulators for rows 0/1
    float S0a = 0.f, ha0a = 0.f, Pa0a = 0.f;
    float S1a = 0.f, ha1a = 0.f, Pa1a = 0.f;
#pragma unroll
    for (int l = 0; l < 6; ++l) {
      if (l == 2) {
        // rec rows 2-4: speculative reads (issued in l==0 tail) verified here
        if (!((__float_as_int(r2.z) >= t) & (__float_as_int(r3.z) >= t) &
              (__float_as_int(r4.z) >= t))) {
          do {
            MEMBAR();
            r2 = recS[2 * 64 + lane]; r3 = recS[3 * 64 + lane]; r4 = recS[4 * 64 + lane];
            MEMBAR();
          } while (!((__float_as_int(r2.z) >= t) & (__float_as_int(r3.z) >= t) &
                     (__float_as_int(r4.z) >= t)));
        }
        ghv[2] = r2.x; hvm1[2] = r2.y;
        ghv[3] = r3.x; hvm1[3] = r3.y;
        ghv[4] = r4.x; hvm1[4] = r4.y;
      }
      const float gh_g = ghv[l];
      const float s = (l == 0) ? (gi0v + gh_g) : dot16i(WBih[l - 1], ns_sg, gh_g);
      const float sg = sig_n(s);                    // r at qg=0, z at qg=1
      const float smg = s - gh_g;                   // scaled i_n at qg=2
      const float sr = qbcast<0>(sg);
      const float sz = qbcast<1>(sg);
      const float nb2 = fmaf(2.f, sz, -2.f);        // -2*(1-z), in exp2 shadow
      const float apb = fmaf(sz, hvm1[l], 1.f);     // z*(h-1) + 1
      const float E = exp2_(fmaf(sr, gh_g, smg));
      const float R = rcp_(E + 1.f);
      ns = fmaf(nb2, R, apb);                       // valid at qg=2 lanes
      if (qg == 2) {
        nsS[wb][l * 16 + kk] = ns;
        if (l == 5) nsOut[(t & 255) * 16 + kk] = ns;
      }
      MEMBAR();
      // ns5 handoff is latency-critical: release gen5 + flag BEFORE readlanes
      if (l == 5 && lane == 0) { sigRel(&gen5[wb], t + 1); sigRel(&flagNs, t * 8 + 6); }
#pragma unroll
      for (int k = 0; k < 16; ++k) ns_sg[k] = rdlane(ns, 4 * k + 2);
      if (l < 5 && lane == 0) sigRel(&flagNs, t * 8 + l + 1);
      if (l == 0) {
        // slack region: housekeeping + prefetch + rec spec reads
        if ((t & 63) == 63) {
          const int cn = (t + 1) >> 6;
          if (cn < 256) pollGE(&flagChunk, cn + 1);
        }
        if ((t & 63) == 32) pollGE(&flagOut, t - 64);
        gpre = chunkS[((t + 1) >> 6) & 1][((t + 1) & 63) * 64 + lane];
        MEMBAR();
        r2 = recS[2 * 64 + lane]; r3 = recS[3 * 64 + lane]; r4 = recS[4 * 64 + lane];
        MEMBAR();
      }
      if (l == 3 || l == 4) {
        // rows 0/1 j-term computed in the spine's latency bubbles (ns_j in regs)
        const float nsq = qbcast<2>(ns);            // ns_j[kk] per lane
        float uj0 = dot16i(Wa0R, ns_sg, ba0R);
        float uj1 = dot16i(Wa1R, ns_sg, ba1R);
        float Pj0 = dot16r(Wh0R, ns_sg);
        float Pj1 = dot16r(Wh1R, ns_sg);
        float pj0 = va0R * tanh_p(uj0);
        float pj1 = va1R * tanh_p(uj1);
        float rj0 = rowsum16(pj0);
        float rj1 = rowsum16(pj1);
        float ej0 = (rdlane(rj0, 0) + rdlane(rj0, 16)) + (rdlane(rj0, 32) + rdlane(rj0, 48));
        float ej1 = (rdlane(rj1, 0) + rdlane(rj1, 16)) + (rdlane(rj1, 32) + rdlane(rj1, 48));
        float wj0_ = exp2_(ej0), wj1_ = exp2_(ej1);
        S0a += wj0_; ha0a = fmaf(wj0_, nsq, ha0a); Pa0a = fmaf(wj0_, Pj0, Pa0a);
        S1a += wj1_; ha1a = fmaf(wj1_, nsq, ha1a); Pa1a = fmaf(wj1_, Pj1, Pa1a);
      }
    }
    // ---- post-layer-5: row5 state + in-chain row0/row1 j5 tails ----
    MEMBAR();
    float4 q0 = partS[0 * 64 + lane], q2 = partS[2 * 64 + lane];
    MEMBAR();
    const float hv5n = qbcast<2>(ns);
    gh5reg = dot16i(WB5, ns_sg, bhh5R);
    float u0 = dot16i(Wa0R, ns_sg, ba0R);
    float u1 = dot16i(Wa1R, ns_sg, ba1R);
    float P0 = dot16r(Wh0R, ns_sg);
    float P1 = dot16r(Wh1R, ns_sg);
    float pe0 = va0R * tanh_p(u0);
    float pe1 = va1R * tanh_p(u1);
    float rs0 = rowsum16(pe0);
    float rs1 = rowsum16(pe1);
    float e0 = (rdlane(rs0, 0) + rdlane(rs0, 16)) + (rdlane(rs0, 32) + rdlane(rs0, 48));
    float e1 = (rdlane(rs1, 0) + rdlane(rs1, 16)) + (rdlane(rs1, 32) + rdlane(rs1, 48));
    float wj0 = exp2_(e0), wj1 = exp2_(e1);
    const int tp = t + 1;
    if (!((__float_as_int(q0.w) >= tp) & (__float_as_int(q2.w) >= tp))) {
      do {
        MEMBAR();
        q0 = partS[0 * 64 + lane]; q2 = partS[2 * 64 + lane];
        MEMBAR();
      } while (!((__float_as_int(q0.w) >= tp) & (__float_as_int(q2.w) >= tp)));
    }
    float S0 = q0.x + S0a + wj0;
    float hT0 = q0.y + ha0a + wj0 * hv5n;
    float PT0 = q0.z + Pa0a + wj0 * P0;
    float S1 = q2.x + S1a + wj1;
    float hT1 = q2.y + ha1a + wj1 * hv5n;
    float PT1 = q2.z + Pa1a + wj1 * P1;
    const float inv0 = rcp_(S0);
    const float inv1 = rcp_(S1);
    gh0n = fmaf(PT0, inv0, bb0); hv0m = fmaf(hT0, inv0, -1.f);
    gh1n = fmaf(PT1, inv1, bb1); hv1m = fmaf(hT1, inv1, -1.f);
    hv5m = hv5n - 1.f;
    gnext = gpre;
  }
}

extern "C" void kernel_launch(void* const* d_in, const int* in_sizes, int n_in,
                              void* d_out, int out_size, void* d_ws, size_t ws_size,
                              hipStream_t stream) {
  const float* batch = (const float*)d_in[0];
  const float* h0    = (const float*)d_in[1];
  const float* Wih0  = (const float*)d_in[2];
  const float* Whh0  = (const float*)d_in[3];
  const float* bih0  = (const float*)d_in[4];
  const float* bhh0  = (const float*)d_in[5];
  const float* Wih   = (const float*)d_in[6];
  const float* Whh   = (const float*)d_in[7];
  const float* bih   = (const float*)d_in[8];
  const float* bhh   = (const float*)d_in[9];
  const float* Wa    = (const float*)d_in[10];
  const float* ba    = (const float*)d_in[11];
  const float* va    = (const float*)d_in[12];
  const float* fc1w  = (const float*)d_in[13];
  const float* fc1b  = (const float*)d_in[14];
  const float* fc2w  = (const float*)d_in[15];
  const float* fc2b  = (const float*)d_in[16];
  float* out = (float*)d_out;
  (void)in_sizes; (void)n_in; (void)out_size; (void)d_ws; (void)ws_size;

  gi0_gemm<<<TT / 64, 256, 0, stream>>>(batch, Wih0, bih0);
  fbrnn_scan<<<1, 512, 0, stream>>>(h0, Whh0, bhh0, Wih, Whh, bih, bhh,
                                    Wa, ba, va, fc1w, fc1b, fc2w, fc2b, out);
}

// Round 6
// 27454.742 us; speedup vs baseline: 2.4059x; 1.0032x over previous
//
#include <hip/hip_runtime.h>
#include <cstdint>
#include <cstddef>

// FBRNN: T=16384, F=2048, H=16, A=64, L=6, G=3H=48.
// R14: chain = pure uniform 6-layer spine (ALL combine work off-wave).
// Measured slope (R13): +120 chain instrs = +800 cy/step -> shed the ~180-instr
// post-layer-5 tail to w1 ("finisher"), re-adding one rec0/rec1 handoff hop.
// w1 reads ns5 from LDS (already broadcast) -> needs NO readlanes for its dots.
// Role map:
//   w0 = chain: 6 layers, gh/h via recS[0..5]; no post-tail; no l5 readlanes
//   w1 = finisher: gen5 wide-spin -> row0/row1 j5 + gh5 -> rec0, rec1, rec5
//   w4 = streamer only (quiet SIMD0 partner)
//   w6 = row0 {j0,j1,j2}->P0A(s0), row0 {j4}->P0C(s2), fc head
//   w2 = row1 {j1,j2}->P1A(s3), row0 {j3}->P0B(s1)
//   w5 = row1 {j3}->P1B(s4), row4 tail {j4,j5}->rec4
//   w7 = row3 {j3}, row1 {j4}->P1C(s5), row3 {j4,j5}->rec3
//   w3 = row2 tail {j2,j3,j4,j5}->rec2

#define TT 16384
#define FF 2048
#define HH 16
#define LL 6
#define GG 48
#define CHUNK 64
#define LOG2E 1.44269504088896340736f

__device__ float g_gi0p[(TT + CHUNK) * 64];

__device__ __forceinline__ float exp2_(float x) { return __builtin_amdgcn_exp2f(x); }
__device__ __forceinline__ float rcp_(float x) { return __builtin_amdgcn_rcpf(x); }
__device__ __forceinline__ float sig_n(float s) { return rcp_(1.f + exp2_(s)); }
__device__ __forceinline__ float tanh_p(float s) { return fmaf(-2.f, rcp_(exp2_(s) + 1.f), 1.f); }

#define MEMBAR() __asm__ __volatile__("" ::: "memory")

__device__ __forceinline__ float rdlane(float v, int l) {
  union { float f; int i; } a, b;
  a.f = v; b.i = __builtin_amdgcn_readlane(a.i, l); return b.f;
}
template <int CTRL>
__device__ __forceinline__ float dppf(float v) {
  union { float f; int i; } a, b;
  a.f = v; b.i = __builtin_amdgcn_mov_dpp(a.i, CTRL, 0xF, 0xF, true); return b.f;
}
template <int Q>
__device__ __forceinline__ float qbcast(float v) { return dppf<Q | (Q << 2) | (Q << 4) | (Q << 6)>(v); }

__device__ __forceinline__ float rowsum16(float v) {
  v += dppf<0xB1>(v);
  v += dppf<0x4E>(v);
  v += dppf<0x141>(v);
  v += dppf<0x140>(v);
  return v;
}
__device__ __forceinline__ float dot16r(const float (&w)[16], const float (&h)[16]) {
  float s0 = w[0] * h[0], s1 = w[1] * h[1], s2 = w[2] * h[2], s3 = w[3] * h[3];
#pragma unroll
  for (int k = 4; k < 16; k += 4) {
    s0 = fmaf(w[k], h[k], s0);       s1 = fmaf(w[k + 1], h[k + 1], s1);
    s2 = fmaf(w[k + 2], h[k + 2], s2); s3 = fmaf(w[k + 3], h[k + 3], s3);
  }
  return (s0 + s1) + (s2 + s3);
}
__device__ __forceinline__ float dot16i(const float (&w)[16], const float (&h)[16], float init) {
  float s0 = fmaf(w[0], h[0], init), s1 = w[1] * h[1], s2 = w[2] * h[2], s3 = w[3] * h[3];
#pragma unroll
  for (int k = 4; k < 16; k += 4) {
    s0 = fmaf(w[k], h[k], s0);       s1 = fmaf(w[k + 1], h[k + 1], s1);
    s2 = fmaf(w[k + 2], h[k + 2], s2); s3 = fmaf(w[k + 3], h[k + 3], s3);
  }
  return (s0 + s1) + (s2 + s3);
}

__device__ __forceinline__ int ldAcq(int* f) {
  return __hip_atomic_load(f, __ATOMIC_ACQUIRE, __HIP_MEMORY_SCOPE_WORKGROUP);
}
__device__ __forceinline__ void pollGE(int* f, int target) {
  while (ldAcq(f) < target) {}
}
__device__ __forceinline__ void waitFlag(int* f, int& cache, int need) {
  if (cache < need) { do { cache = ldAcq(f); } while (cache < need); }
}
// relaxed flag store: LDS ds ops are in-order per wave; MEMBAR() pins compile order.
__device__ __forceinline__ void sigRel(int* f, int v) {
  __hip_atomic_store(f, v, __ATOMIC_RELAXED, __HIP_MEMORY_SCOPE_WORKGROUP);
}

// one softmax term: energies over 64 attention lanes, P = Wh.nr per G-lane.
__device__ __forceinline__ void combBlock(const float4 A0, const float4 A1, const float4 A2,
                                          const float4 A3, float nsv,
                                          const float (&Wa)[16], float ba, float va,
                                          const float (&Wh)[16],
                                          float& S, float& ha, float& Pa) {
  float nr[16] = {A0.x, A0.y, A0.z, A0.w, A1.x, A1.y, A1.z, A1.w,
                  A2.x, A2.y, A2.z, A2.w, A3.x, A3.y, A3.z, A3.w};
  float u = dot16i(Wa, nr, ba);
  float P = dot16r(Wh, nr);
  float pe = va * tanh_p(u);
  float r = rowsum16(pe);
  float e = (rdlane(r, 0) + rdlane(r, 16)) + (rdlane(r, 32) + rdlane(r, 48));
  float w = exp2_(e);
  S += w; ha = fmaf(w, nsv, ha); Pa = fmaf(w, P, Pa);
}

// ---------------- Phase 1: gi0 GEMM (permuted + gate-prescaled output) ----------------
__global__ __launch_bounds__(256) void gi0_gemm(const float* __restrict__ X,
                                                const float* __restrict__ W,
                                                const float* __restrict__ bias) {
  __shared__ float xs[64][132];
  __shared__ float ws[48][132];
  const int tid = threadIdx.x;
  const int t0 = blockIdx.x * 64;
  const int tg = tid & 15;
  const int tt = tid >> 4;
  float acc[4][3];
#pragma unroll
  for (int u = 0; u < 4; ++u)
#pragma unroll
    for (int v = 0; v < 3; ++v) acc[u][v] = 0.f;

  for (int k0 = 0; k0 < FF; k0 += 128) {
#pragma unroll
    for (int i = 0; i < 32; ++i) {
      int e = tid + 256 * i; int r = e >> 7, c = e & 127;
      xs[r][c] = X[(size_t)(t0 + r) * FF + k0 + c];
    }
#pragma unroll
    for (int i = 0; i < 24; ++i) {
      int e = tid + 256 * i; int r = e >> 7, c = e & 127;
      ws[r][c] = W[(size_t)r * FF + k0 + c];
    }
    __syncthreads();
#pragma unroll 8
    for (int c = 0; c < 128; ++c) {
      float x0 = xs[tt][c], x1 = xs[tt + 16][c], x2 = xs[tt + 32][c], x3 = xs[tt + 48][c];
      float w0 = ws[tg][c], w1 = ws[tg + 16][c], w2 = ws[tg + 32][c];
      acc[0][0] += x0 * w0; acc[0][1] += x0 * w1; acc[0][2] += x0 * w2;
      acc[1][0] += x1 * w0; acc[1][1] += x1 * w1; acc[1][2] += x1 * w2;
      acc[2][0] += x2 * w0; acc[2][1] += x2 * w1; acc[2][2] += x2 * w2;
      acc[3][0] += x3 * w0; acc[3][1] += x3 * w1; acc[3][2] += x3 * w2;
    }
    __syncthreads();
  }
  const float gsc3[3] = {-LOG2E, -LOG2E, 2.f * LOG2E};
#pragma unroll
  for (int u = 0; u < 4; ++u)
#pragma unroll
    for (int v = 0; v < 3; ++v)
      g_gi0p[(size_t)(t0 + tt + 16 * u) * 64 + tg * 4 + v] =
          (acc[u][v] + bias[tg + 16 * v]) * gsc3[v];
}

// ---------------- Phase 2: barrier-free sequential scan ----------------
__global__ __launch_bounds__(512, 1) void fbrnn_scan(
    const float* __restrict__ h0,
    const float* __restrict__ Whh0, const float* __restrict__ bhh0,
    const float* __restrict__ Wih, const float* __restrict__ Whh,
    const float* __restrict__ bih, const float* __restrict__ bhh,
    const float* __restrict__ Wa, const float* __restrict__ ba,
    const float* __restrict__ va,
    const float* __restrict__ fc1w, const float* __restrict__ fc1b,
    const float* __restrict__ fc2w, const float* __restrict__ fc2b,
    float* __restrict__ out) {
  __shared__ __align__(16) float nsS[2][LL * HH];     // ns, buf = t&1
  __shared__ __align__(16) float4 recS[6 * 64];       // rows 0..5: {gh, h-1, stamp, pad}
  __shared__ __align__(16) float4 partS[6 * 64];      // {S, ha, Pa, stamp}
  __shared__ __align__(16) float nsOut[256 * HH];     // ns5 ring for fc (w6)
  __shared__ __align__(16) float chunkS[2][CHUNK * 64];
  __shared__ int flagNs;      // chain: t*8 + l + 1 after ns_l visible
  __shared__ int flagChunk;   // streamer: c+1 after chunk c staged
  __shared__ int flagOut;     // w6: t+1 after out[t] stored
  __shared__ int gen5[2];     // chain: t+1 after ns5 of step t stored in nsS[t&1]

  const int tid = threadIdx.x;
  const int wv = tid >> 6;
  const int lane = tid & 63;
  const int qg = lane & 3;
  const int kk = lane >> 2;
  const int gate = (qg < 3 ? qg : 2);
  const int G = gate * 16 + kk;
  const float gsc = (gate == 2) ? 2.f * LOG2E : -LOG2E;

  const bool isChain = (wv == 0);
  const bool isFin = (wv == 1);
  const bool isStream = (wv == 4);
  const bool isFc = (wv == 6);
  const int tailRow = (wv == 3) ? 2 : (wv == 7) ? 3 : (wv == 5) ? 4 : -1;

  // ---- per-role register weights (prescaled; bih folded into gh bases) ----
  float WBih[5][16];                          // chain only
  float WB5[16];  float bhh5R = 0.f;          // finisher: Whh layer-5 row
  float Wa0R[16], Wh0R[16], Wa1R[16], Wh1R[16];  // finisher rows 0/1
  float ba0R = 0.f, va0R = 0.f, bb0 = 0.f;
  float ba1R = 0.f, va1R = 0.f, bb1 = 0.f;
  float WaA[16], WhA[16]; float baA = 0.f, vaA = 0.f;   // helper row A
  float WaB[16], WhB[16]; float baB = 0.f, vaB = 0.f;   // helper row B
  float WaT[16], WhT[16]; float baT = 0.f, vaT = 0.f, bhT = 0.f;  // tail row
  float fc1R[16]; float fb1 = 0.f, fw2 = 0.f, fb2 = 0.f;

#define LOADROW(R, WaX, baX, vaX, WhX) do {                                      \
    _Pragma("unroll") for (int k = 0; k < 16; ++k)                               \
      WaX[k] = Wa[((R) * 16 + k) * 64 + lane] * (2.f * LOG2E);                   \
    baX = ba[(R) * 64 + lane] * (2.f * LOG2E);                                   \
    vaX = va[(R) * 64 + lane] * LOG2E;                                           \
    { const float* ws_ = ((R) == 0) ? (Whh0 + G * 16)                            \
                                    : (Whh + (((R) - 1) * GG + G) * 16);         \
      _Pragma("unroll") for (int k = 0; k < 16; ++k) WhX[k] = ws_[k] * gsc; }    \
  } while (0)
#define LOADBH(R, bhX) do {                                                      \
    bhX = (((R) == 0) ? bhh0[G]                                                  \
                      : (bhh[((R) - 1) * GG + G] + bih[((R) - 1) * GG + G])) *   \
          gsc;                                                                   \
  } while (0)

  if (isChain) {
#pragma unroll
    for (int l = 0; l < 5; ++l)
#pragma unroll
      for (int k = 0; k < 16; ++k) WBih[l][k] = Wih[((l * GG) + G) * 16 + k] * gsc;
  } else if (isFin) {
#pragma unroll
    for (int k = 0; k < 16; ++k) WB5[k] = Whh[(4 * GG + G) * 16 + k] * gsc;
    bhh5R = (bhh[4 * GG + G] + bih[4 * GG + G]) * gsc;
    LOADROW(0, Wa0R, ba0R, va0R, Wh0R); LOADBH(0, bb0);
    LOADROW(1, Wa1R, ba1R, va1R, Wh1R); LOADBH(1, bb1);
  } else if (isFc) {
    LOADROW(0, WaA, baA, vaA, WhA);
    const int m = lane & 31;
#pragma unroll
    for (int k = 0; k < 16; ++k) fc1R[k] = fc1w[m * 16 + k];
    fb1 = fc1b[m]; fw2 = fc2w[m]; fb2 = fc2b[0];
  } else if (wv == 2) {
    LOADROW(1, WaA, baA, vaA, WhA);
    LOADROW(0, WaB, baB, vaB, WhB);
  } else if (wv == 3) {
    LOADROW(2, WaT, baT, vaT, WhT); LOADBH(2, bhT);
  } else if (wv == 5) {
    LOADROW(1, WaA, baA, vaA, WhA);
    LOADROW(4, WaT, baT, vaT, WhT); LOADBH(4, bhT);
  } else if (wv == 7) {
    LOADROW(1, WaA, baA, vaA, WhA);
    LOADROW(3, WaT, baT, vaT, WhT); LOADBH(3, bhT);
  }

  if (tid == 0) { flagNs = 0; flagChunk = 1; flagOut = 0; gen5[0] = 0; gen5[1] = 0; }

  // ---- initial recs / partials ----
  if (isFin) {
    float hr[16];
#pragma unroll
    for (int k = 0; k < 16; ++k) hr[k] = h0[0 * 16 + k];
    float4 r0i; r0i.x = dot16i(Wh0R, hr, bb0); r0i.y = h0[0 * 16 + kk] - 1.f;
    r0i.z = __int_as_float(0); r0i.w = 0.f;
    recS[0 * 64 + lane] = r0i;
#pragma unroll
    for (int k = 0; k < 16; ++k) hr[k] = h0[1 * 16 + k];
    float4 r1i; r1i.x = dot16i(Wh1R, hr, bb1); r1i.y = h0[1 * 16 + kk] - 1.f;
    r1i.z = __int_as_float(0); r1i.w = 0.f;
    recS[1 * 64 + lane] = r1i;
#pragma unroll
    for (int k = 0; k < 16; ++k) hr[k] = h0[5 * 16 + k];
    float4 r5i; r5i.x = dot16i(WB5, hr, bhh5R); r5i.y = h0[5 * 16 + kk] - 1.f;
    r5i.z = __int_as_float(0); r5i.w = 0.f;
    recS[5 * 64 + lane] = r5i;
  } else if (tailRow >= 0) {
    float hr[16];
#pragma unroll
    for (int k = 0; k < 16; ++k) hr[k] = h0[tailRow * 16 + k];
    float4 rr;
    rr.x = dot16i(WhT, hr, bhT);
    rr.y = h0[tailRow * 16 + kk] - 1.f;
    rr.z = __int_as_float(0);
    rr.w = 0.f;
    recS[tailRow * 64 + lane] = rr;
  }
  if (isStream) {
    const float4* src = (const float4*)g_gi0p;
    float4* dst = (float4*)(&chunkS[0][0]);
#pragma unroll
    for (int q = 0; q < 16; ++q) dst[q * 64 + lane] = src[q * 64 + lane];
  }
  if (isFc) {
#pragma unroll
    for (int s = 0; s < 6; ++s)
      partS[s * 64 + lane] = make_float4(0.f, 0.f, 0.f, __int_as_float(0));
  }
  __syncthreads();  // the only barrier

// early combine block: wait flag (single-dword spin), read nsS row J, accumulate
#define EBLOCK(J, WaX, baX, vaX, WhX, Sx, hax, Pax) do {                          \
    waitFlag(&flagNs, fcache, t * 8 + (J) + 1);                                   \
    const float4* np_ = (const float4*)&nsS[nb][(J) * 16];                        \
    float4 A0_ = np_[0], A1_ = np_[1], A2_ = np_[2], A3_ = np_[3];                \
    float nsv_ = nsS[nb][(J) * 16 + kk];                                          \
    combBlock(A0_, A1_, A2_, A3_, nsv_, WaX, baX, vaX, WhX, Sx, hax, Pax);        \
  } while (0)

#define POSTP(SLOT, Sx, hax, Pax) do {                                            \
    MEMBAR();                                                                     \
    partS[(SLOT) * 64 + lane] = make_float4(Sx, hax, Pax, __int_as_float(t + 1)); \
    MEMBAR();                                                                     \
  } while (0)

// j=5 tail (row weights T): gen5 wide-spin, accumulate, finalize, write rec
#define TAILFIN(ROW, Sv, hav, Pav) do {                                           \
    float4 A0, A1, A2, A3; float nsv5;                                            \
    for (;;) {                                                                    \
      int g5 = ldAcq(&gen5[nb]);                                                  \
      MEMBAR();                                                                   \
      const float4* np = (const float4*)&nsS[nb][5 * 16];                         \
      A0 = np[0]; A1 = np[1]; A2 = np[2]; A3 = np[3];                             \
      nsv5 = nsS[nb][5 * 16 + kk];                                                \
      MEMBAR();                                                                   \
      if (g5 >= tgt) break;                                                       \
    }                                                                             \
    combBlock(A0, A1, A2, A3, nsv5, WaT, baT, vaT, WhT, Sv, hav, Pav);            \
    const float inv_ = rcp_(Sv);                                                  \
    float4 rr_; rr_.x = fmaf(Pav, inv_, bhT); rr_.y = fmaf(hav, inv_, -1.f);      \
    rr_.z = __int_as_float(tgt); rr_.w = 0.f;                                     \
    recS[(ROW) * 64 + lane] = rr_;                                                \
  } while (0)

  // ================= streamer (w4, quiet SIMD0 partner) =================
  if (isStream) {
#pragma unroll 1
    for (int c = 1; c < 256; ++c) {
      if (c >= 2) pollGE(&flagNs, ((c - 1) * 64 - 1) * 8 + 1);
      const float4* src = (const float4*)(g_gi0p + ((size_t)c << 12));
      float4* dst = (float4*)(&chunkS[c & 1][0]);
#pragma unroll
      for (int q = 0; q < 16; ++q) dst[q * 64 + lane] = src[q * 64 + lane];
      MEMBAR();
      sigRel(&flagChunk, c + 1);
    }
    return;
  }

  // ================= w1: finisher (rows 0/1 j5 + gh5 -> rec0, rec1, rec5) ====
  if (isFin) {
#pragma unroll 1
    for (int t = 0; t < TT; ++t) {
      const int nb = t & 1;
      const int tgt = t + 1;
      float4 A0, A1, A2, A3; float nsv5;
      for (;;) {
        int g5 = ldAcq(&gen5[nb]);
        MEMBAR();
        const float4* np = (const float4*)&nsS[nb][5 * 16];
        A0 = np[0]; A1 = np[1]; A2 = np[2]; A3 = np[3];
        nsv5 = nsS[nb][5 * 16 + kk];
        MEMBAR();
        if (g5 >= tgt) break;
      }
      float nr[16] = {A0.x, A0.y, A0.z, A0.w, A1.x, A1.y, A1.z, A1.w,
                      A2.x, A2.y, A2.z, A2.w, A3.x, A3.y, A3.z, A3.w};
      float u0 = dot16i(Wa0R, nr, ba0R);
      float u1 = dot16i(Wa1R, nr, ba1R);
      float P0 = dot16r(Wh0R, nr);
      float P1 = dot16r(Wh1R, nr);
      float g5d = dot16i(WB5, nr, bhh5R);
      float pe0 = va0R * tanh_p(u0);
      float pe1 = va1R * tanh_p(u1);
      float rs0 = rowsum16(pe0);
      float rs1 = rowsum16(pe1);
      float e0 = (rdlane(rs0, 0) + rdlane(rs0, 16)) + (rdlane(rs0, 32) + rdlane(rs0, 48));
      float e1 = (rdlane(rs1, 0) + rdlane(rs1, 16)) + (rdlane(rs1, 32) + rdlane(rs1, 48));
      float wj0 = exp2_(e0), wj1 = exp2_(e1);
      // partials (usually already fresh)
      float4 q0, q1, q2, q3, q4, q5;
      for (;;) {
        MEMBAR();
        q0 = partS[0 * 64 + lane]; q1 = partS[1 * 64 + lane]; q2 = partS[2 * 64 + lane];
        q3 = partS[3 * 64 + lane]; q4 = partS[4 * 64 + lane]; q5 = partS[5 * 64 + lane];
        MEMBAR();
        int ok = (__float_as_int(q0.w) >= tgt) & (__float_as_int(q1.w) >= tgt) &
                 (__float_as_int(q2.w) >= tgt) & (__float_as_int(q3.w) >= tgt) &
                 (__float_as_int(q4.w) >= tgt) & (__float_as_int(q5.w) >= tgt);
        if (ok) break;
      }
      float S0 = q0.x + q1.x + q2.x + wj0;
      float hT0 = q0.y + q1.y + q2.y + wj0 * nsv5;
      float PT0 = q0.z + q1.z + q2.z + wj0 * P0;
      float S1 = q3.x + q4.x + q5.x + wj1;
      float hT1 = q3.y + q4.y + q5.y + wj1 * nsv5;
      float PT1 = q3.z + q4.z + q5.z + wj1 * P1;
      const float inv0 = rcp_(S0);
      const float inv1 = rcp_(S1);
      float4 w0r; w0r.x = fmaf(PT0, inv0, bb0); w0r.y = fmaf(hT0, inv0, -1.f);
      w0r.z = __int_as_float(tgt); w0r.w = 0.f;
      float4 w1r; w1r.x = fmaf(PT1, inv1, bb1); w1r.y = fmaf(hT1, inv1, -1.f);
      w1r.z = __int_as_float(tgt); w1r.w = 0.f;
      float4 w5r; w5r.x = g5d; w5r.y = nsv5 - 1.f;
      w5r.z = __int_as_float(tgt); w5r.w = 0.f;
      MEMBAR();
      recS[0 * 64 + lane] = w0r;
      recS[1 * 64 + lane] = w1r;
      recS[5 * 64 + lane] = w5r;
      MEMBAR();
    }
    return;
  }

  // ================= w6: row0 {j0,j1,j2}->s0, {j4}->s2, fc head =============
  if (isFc) {
    int fcache = 0;
#pragma unroll 1
    for (int t = 0; t < TT; ++t) {
      const int nb = t & 1;
      float S = 0.f, ha = 0.f, Pa = 0.f;
      EBLOCK(0, WaA, baA, vaA, WhA, S, ha, Pa);
      EBLOCK(1, WaA, baA, vaA, WhA, S, ha, Pa);
      EBLOCK(2, WaA, baA, vaA, WhA, S, ha, Pa);
      POSTP(0, S, ha, Pa);
      S = 0.f; ha = 0.f; Pa = 0.f;
      EBLOCK(4, WaA, baA, vaA, WhA, S, ha, Pa);
      POSTP(2, S, ha, Pa);
      // fc tail
      waitFlag(&flagNs, fcache, t * 8 + 6);
      const float4* np = (const float4*)(nsOut + (t & 255) * 16);
      float4 a0 = np[0], a1 = np[1], a2 = np[2], a3 = np[3];
      float nrf[16] = {a0.x, a0.y, a0.z, a0.w, a1.x, a1.y, a1.z, a1.w,
                       a2.x, a2.y, a2.z, a2.w, a3.x, a3.y, a3.z, a3.w};
      float y = dot16i(fc1R, nrf, fb1);
      float p = rowsum16(y * fw2);
      float o = rdlane(p, 0) + rdlane(p, 16) + fb2;
      if (lane == 0) out[t] = o;
      MEMBAR();
      sigRel(&flagOut, t + 1);
    }
    return;
  }

  // ================= combine / partial waves =================
  if (!isChain) {
    int fcache = 0;
    if (wv == 2) {         // row1 {j1,j2}->s3, row0 {j3}->s1
#pragma unroll 1
      for (int t = 0; t < TT; ++t) {
        const int nb = t & 1;
        float S = 0.f, ha = 0.f, Pa = 0.f;
        EBLOCK(1, WaA, baA, vaA, WhA, S, ha, Pa);
        EBLOCK(2, WaA, baA, vaA, WhA, S, ha, Pa);
        POSTP(3, S, ha, Pa);
        S = 0.f; ha = 0.f; Pa = 0.f;
        EBLOCK(3, WaB, baB, vaB, WhB, S, ha, Pa);
        POSTP(1, S, ha, Pa);
      }
    } else if (wv == 5) {  // row1 {j3}->s4, row4 tail {j4,j5}->rec4
#pragma unroll 1
      for (int t = 0; t < TT; ++t) {
        const int nb = t & 1;
        const int tgt = t + 1;
        float S = 0.f, ha = 0.f, Pa = 0.f;
        EBLOCK(3, WaA, baA, vaA, WhA, S, ha, Pa);
        POSTP(4, S, ha, Pa);
        S = 0.f; ha = 0.f; Pa = 0.f;
        EBLOCK(4, WaT, baT, vaT, WhT, S, ha, Pa);
        TAILFIN(4, S, ha, Pa);
      }
    } else if (wv == 7) {  // row3 {j3}, row1 {j4}->s5, row3 {j4,j5}->rec3
#pragma unroll 1
      for (int t = 0; t < TT; ++t) {
        const int nb = t & 1;
        const int tgt = t + 1;
        float S = 0.f, ha = 0.f, Pa = 0.f;
        EBLOCK(3, WaT, baT, vaT, WhT, S, ha, Pa);
        float Sb = 0.f, hab = 0.f, Pab = 0.f;
        EBLOCK(4, WaA, baA, vaA, WhA, Sb, hab, Pab);
        POSTP(5, Sb, hab, Pab);
        EBLOCK(4, WaT, baT, vaT, WhT, S, ha, Pa);
        TAILFIN(3, S, ha, Pa);
      }
    } else {               // wv == 3: row2 tail {j2,j3,j4,j5}->rec2
#pragma unroll 1
      for (int t = 0; t < TT; ++t) {
        const int nb = t & 1;
        const int tgt = t + 1;
        float S = 0.f, ha = 0.f, Pa = 0.f;
        EBLOCK(2, WaT, baT, vaT, WhT, S, ha, Pa);
        EBLOCK(3, WaT, baT, vaT, WhT, S, ha, Pa);
        EBLOCK(4, WaT, baT, vaT, WhT, S, ha, Pa);
        TAILFIN(2, S, ha, Pa);
      }
    }
    return;
  }

  // ================= GRU chain (w0): pure 6-layer spine =================
  float gnext = chunkS[0][lane];
  float ns_sg[16];
#pragma unroll 1
  for (int t = 0; t < TT; ++t) {
    const int wb = t & 1;

    // housekeeping before the rec0/rec1 wait
    if ((t & 63) == 63) {
      const int cn = (t + 1) >> 6;
      if (cn < 256) pollGE(&flagChunk, cn + 1);
    }
    if ((t & 63) == 32) pollGE(&flagOut, t - 64);
    const float gpre = chunkS[((t + 1) >> 6) & 1][((t + 1) & 63) * 64 + lane];

    // wait rec0/rec1 (stamp >= t): single-round-trip (stamp inside the b128)
    float4 r0, r1;
    for (;;) {
      MEMBAR();
      r0 = recS[0 * 64 + lane]; r1 = recS[1 * 64 + lane];
      MEMBAR();
      if ((__float_as_int(r0.z) >= t) & (__float_as_int(r1.z) >= t)) break;
    }
    float ghv[6], hvm1[6];
    ghv[0] = r0.x; hvm1[0] = r0.y;
    ghv[1] = r1.x; hvm1[1] = r1.y;
    float4 r2, r3, r4, r5;
    float gi0v = gnext;
    float ns = 0.f;
#pragma unroll
    for (int l = 0; l < 6; ++l) {
      if (l == 2) {
        if (!((__float_as_int(r2.z) >= t) & (__float_as_int(r3.z) >= t) &
              (__float_as_int(r4.z) >= t) & (__float_as_int(r5.z) >= t))) {
          do {
            MEMBAR();
            r2 = recS[2 * 64 + lane]; r3 = recS[3 * 64 + lane];
            r4 = recS[4 * 64 + lane]; r5 = recS[5 * 64 + lane];
            MEMBAR();
          } while (!((__float_as_int(r2.z) >= t) & (__float_as_int(r3.z) >= t) &
                     (__float_as_int(r4.z) >= t) & (__float_as_int(r5.z) >= t)));
        }
        ghv[2] = r2.x; hvm1[2] = r2.y;
        ghv[3] = r3.x; hvm1[3] = r3.y;
        ghv[4] = r4.x; hvm1[4] = r4.y;
        ghv[5] = r5.x; hvm1[5] = r5.y;
      }
      const float gh_g = ghv[l];
      const float s = (l == 0) ? (gi0v + gh_g) : dot16i(WBih[l - 1], ns_sg, gh_g);
      const float sg = sig_n(s);                    // r at qg=0, z at qg=1
      const float smg = s - gh_g;                   // scaled i_n at qg=2
      const float sr = qbcast<0>(sg);
      const float sz = qbcast<1>(sg);
      const float nb2 = fmaf(2.f, sz, -2.f);        // -2*(1-z), in exp2 shadow
      const float apb = fmaf(sz, hvm1[l], 1.f);     // z*(h-1) + 1
      const float E = exp2_(fmaf(sr, gh_g, smg));
      const float R = rcp_(E + 1.f);
      ns = fmaf(nb2, R, apb);                       // valid at qg=2 lanes
      if (qg == 2) {
        nsS[wb][l * 16 + kk] = ns;
        if (l == 5) nsOut[(t & 255) * 16 + kk] = ns;
      }
      MEMBAR();
      if (l == 5) {
        if (lane == 0) { sigRel(&gen5[wb], t + 1); sigRel(&flagNs, t * 8 + 6); }
      } else {
#pragma unroll
        for (int k = 0; k < 16; ++k) ns_sg[k] = rdlane(ns, 4 * k + 2);
        if (lane == 0) sigRel(&flagNs, t * 8 + l + 1);
      }
      if (l == 0) {
        // speculative rec reads for rows 2..5 (verified at l==2)
        MEMBAR();
        r2 = recS[2 * 64 + lane]; r3 = recS[3 * 64 + lane];
        r4 = recS[4 * 64 + lane]; r5 = recS[5 * 64 + lane];
        MEMBAR();
      }
    }
    gnext = gpre;
  }
}

extern "C" void kernel_launch(void* const* d_in, const int* in_sizes, int n_in,
                              void* d_out, int out_size, void* d_ws, size_t ws_size,
                              hipStream_t stream) {
  const float* batch = (const float*)d_in[0];
  const float* h0    = (const float*)d_in[1];
  const float* Wih0  = (const float*)d_in[2];
  const float* Whh0  = (const float*)d_in[3];
  const float* bih0  = (const float*)d_in[4];
  const float* bhh0  = (const float*)d_in[5];
  const float* Wih   = (const float*)d_in[6];
  const float* Whh   = (const float*)d_in[7];
  const float* bih   = (const float*)d_in[8];
  const float* bhh   = (const float*)d_in[9];
  const float* Wa    = (const float*)d_in[10];
  const float* ba    = (const float*)d_in[11];
  const float* va    = (const float*)d_in[12];
  const float* fc1w  = (const float*)d_in[13];
  const float* fc1b  = (const float*)d_in[14];
  const float* fc2w  = (const float*)d_in[15];
  const float* fc2b  = (const float*)d_in[16];
  float* out = (float*)d_out;
  (void)in_sizes; (void)n_in; (void)out_size; (void)d_ws; (void)ws_size;

  gi0_gemm<<<TT / 64, 256, 0, stream>>>(batch, Wih0, bih0);
  fbrnn_scan<<<1, 512, 0, stream>>>(h0, Whh0, bhh0, Wih, Whh, bih, bhh,
                                    Wa, ba, va, fc1w, fc1b, fc2w, fc2b, out);
}